// Round 4
// baseline (286.685 us; speedup 1.0000x reference)
//
#include <hip/hip_runtime.h>
#include <hip/hip_bf16.h>
#include <cstdint>

// Problem: single attention head, B=4 T=2048 C=1024 H=128, causal, scale = C^-0.5.
// Inputs fp32 (PROVEN: R1 bf16-read NaN'd, R2 sniff->fp32 path finite):
//   x[B,T,C], Wq/Wk/Wv[C,H], mask[T,T] int32 (tril, ignored).
// Output FP32 [B,T,H]  (reference output dtype; R2/R3 bf16 writes decoded as
// fp32 gave the deterministic 4.26 absmax signature).
//
// Pipeline:
//   1) transpose_w: Wt[3][H][C] bf16  (proj B-fragments 16B-contiguous)
//   2) proj_gemm:   q[B,T,H], k[B,T,H] bf16, Vt[B,H,T] bf16 (MFMA 16x16x32)
//   3) attn:        flash online-softmax, 1 wave / 16 Q rows, KV tile 32,
//                   P via LDS (stride 40 shorts), PV from Vt. fp32 out.

typedef __bf16 bf16_t;
typedef __bf16 bf16x8 __attribute__((ext_vector_type(8)));
typedef float f32x4 __attribute__((ext_vector_type(4)));

#define MFMA16(a, b, c) __builtin_amdgcn_mfma_f32_16x16x32_bf16(a, b, c, 0, 0, 0)

constexpr int T = 2048;
constexpr int C = 1024;
constexpr int H = 128;

// 8 contiguous fp32 -> bf16x8 (idx 8-aligned)
__device__ inline bf16x8 load8f(const float* __restrict__ p, size_t idx) {
    const float* q = p + idx;
    float4 a = *(const float4*)q;
    float4 b = *(const float4*)(q + 4);
    bf16x8 r;
    r[0] = (bf16_t)a.x; r[1] = (bf16_t)a.y; r[2] = (bf16_t)a.z; r[3] = (bf16_t)a.w;
    r[4] = (bf16_t)b.x; r[5] = (bf16_t)b.y; r[6] = (bf16_t)b.z; r[7] = (bf16_t)b.w;
    return r;
}

// ---------------------------------------------------------------------------
// Kernel 1: W[C][H] fp32 -> Wt[H][C] bf16. grid (C/32, H/32, 3), block (32,8)
__global__ void transpose_w(const float* __restrict__ Wq,
                            const float* __restrict__ Wk,
                            const float* __restrict__ Wv,
                            bf16_t* __restrict__ Wt) {
    __shared__ bf16_t tile[32][34];
    const float* W = blockIdx.z == 0 ? Wq : (blockIdx.z == 1 ? Wk : Wv);
    const int c0 = blockIdx.x * 32, h0 = blockIdx.y * 32;
    const int tx = threadIdx.x, ty = threadIdx.y;
#pragma unroll
    for (int i = 0; i < 4; i++)
        tile[ty + 8 * i][tx] = (bf16_t)W[(size_t)(c0 + ty + 8 * i) * H + h0 + tx];
    __syncthreads();
    bf16_t* Wtz = Wt + (size_t)blockIdx.z * H * C;
#pragma unroll
    for (int i = 0; i < 4; i++)
        Wtz[(size_t)(h0 + ty + 8 * i) * C + c0 + tx] = tile[tx][ty + 8 * i];
}

// ---------------------------------------------------------------------------
// Kernel 2: y = x @ W, bf16 MFMA. M=8192 K=1024 N=128.
// z in {0:q row-major, 1:k row-major, 2:V transposed -> Vt[B][H][T]}.
// grid (64, 1, 3), block 256
__global__ __launch_bounds__(256) void proj_gemm(const float* __restrict__ x,
                                                 const bf16_t* __restrict__ Wt,
                                                 bf16_t* __restrict__ qout,
                                                 bf16_t* __restrict__ kout,
                                                 bf16_t* __restrict__ vtout) {
    const int wave = threadIdx.x >> 6;
    const int lane = threadIdx.x & 63;
    const int m16 = lane & 15, g = lane >> 4;
    const int z = blockIdx.z;
    const int r0 = blockIdx.x * 128 + wave * 32;
    const bf16_t* Wtz = Wt + (size_t)z * H * C;

    f32x4 zero = {0.f, 0.f, 0.f, 0.f};
    f32x4 acc[2][8];
#pragma unroll
    for (int rt = 0; rt < 2; rt++)
#pragma unroll
        for (int nt = 0; nt < 8; nt++) acc[rt][nt] = zero;

    for (int k0 = 0; k0 < C; k0 += 32) {
        bf16x8 a0 = load8f(x, (size_t)(r0 + m16) * C + k0 + g * 8);
        bf16x8 a1 = load8f(x, (size_t)(r0 + 16 + m16) * C + k0 + g * 8);
#pragma unroll
        for (int nt = 0; nt < 8; nt++) {
            bf16x8 b = *(const bf16x8*)(Wtz + (size_t)(nt * 16 + m16) * C + k0 + g * 8);
            acc[0][nt] = MFMA16(a0, b, acc[0][nt]);
            acc[1][nt] = MFMA16(a1, b, acc[1][nt]);
        }
    }

    if (z < 2) {
        bf16_t* out = (z == 0) ? qout : kout;
#pragma unroll
        for (int rt = 0; rt < 2; rt++)
#pragma unroll
            for (int nt = 0; nt < 8; nt++)
#pragma unroll
                for (int ri = 0; ri < 4; ri++) {
                    int r = r0 + rt * 16 + g * 4 + ri;
                    out[(size_t)r * H + nt * 16 + m16] = (bf16_t)acc[rt][nt][ri];
                }
    } else {
#pragma unroll
        for (int rt = 0; rt < 2; rt++)
#pragma unroll
            for (int ri = 0; ri < 4; ri++) {
                int r = r0 + rt * 16 + g * 4 + ri;
                int b = r >> 11, t = r & (T - 1);
#pragma unroll
                for (int nt = 0; nt < 8; nt++)
                    vtout[((size_t)b * H + nt * 16 + m16) * T + t] = (bf16_t)acc[rt][nt][ri];
            }
    }
}

// ---------------------------------------------------------------------------
// Kernel 3: flash attention, causal. One wave per (batch, 16-row Q tile).
// grid (512), block (64). Reverse-paired q-tile mapping for load balance.
__global__ __launch_bounds__(64) void attn(const bf16_t* __restrict__ q,
                                           const bf16_t* __restrict__ k,
                                           const bf16_t* __restrict__ vt,
                                           float* __restrict__ out) {
    __shared__ __align__(16) bf16_t pbuf[16][40];
    const int lane = threadIdx.x;
    const int m16 = lane & 15, g = lane >> 4;
    const int b = blockIdx.x & 3;
    const int kk = blockIdx.x >> 2;               // 0..127
    const int qt = (kk < 64) ? kk : 191 - kk;     // reverse-pair load balance
    const int q0 = qt * 16;

    const bf16_t* qb = q + (size_t)b * T * H;
    const bf16_t* kb = k + (size_t)b * T * H;
    const bf16_t* vb = vt + (size_t)b * H * T;

    bf16x8 aq[4];
#pragma unroll
    for (int c = 0; c < 4; c++)
        aq[c] = *(const bf16x8*)(qb + (size_t)(q0 + m16) * H + c * 32 + g * 8);

    f32x4 zero = {0.f, 0.f, 0.f, 0.f};
    f32x4 acc[8];
#pragma unroll
    for (int ht = 0; ht < 8; ht++) acc[ht] = zero;
    float mst[4], lst[4];
#pragma unroll
    for (int ri = 0; ri < 4; ri++) { mst[ri] = -1e30f; lst[ri] = 0.f; }

    const int kv_end = q0 + 16;
    for (int kv0 = 0; kv0 < kv_end; kv0 += 32) {
        f32x4 s[2];
        s[0] = zero; s[1] = zero;
#pragma unroll
        for (int t = 0; t < 2; t++)
#pragma unroll
            for (int c = 0; c < 4; c++) {
                bf16x8 bk = *(const bf16x8*)(kb + (size_t)(kv0 + t * 16 + m16) * H + c * 32 + g * 8);
                s[t] = MFMA16(aq[c], bk, s[t]);
            }

        float p0v[4], p1v[4];
#pragma unroll
        for (int ri = 0; ri < 4; ri++) {
            const int row = q0 + g * 4 + ri;
            float v0 = s[0][ri] * 0.03125f;  // C^-0.5 = 1/32
            float v1 = s[1][ri] * 0.03125f;
            if (kv0 + m16 > row) v0 = -1e30f;
            if (kv0 + 16 + m16 > row) v1 = -1e30f;
            float rm = fmaxf(v0, v1);
#pragma unroll
            for (int off = 1; off < 16; off <<= 1) rm = fmaxf(rm, __shfl_xor(rm, off));
            const float mnew = fmaxf(mst[ri], rm);
            const float alpha = __expf(mst[ri] - mnew);
            const float p0 = __expf(v0 - mnew);
            const float p1 = __expf(v1 - mnew);
            float psum = p0 + p1;
#pragma unroll
            for (int off = 1; off < 16; off <<= 1) psum += __shfl_xor(psum, off);
            lst[ri] = lst[ri] * alpha + psum;
            mst[ri] = mnew;
            p0v[ri] = p0; p1v[ri] = p1;
#pragma unroll
            for (int ht = 0; ht < 8; ht++) acc[ht][ri] *= alpha;
        }

        __syncthreads();
#pragma unroll
        for (int ri = 0; ri < 4; ri++) {
            pbuf[g * 4 + ri][m16] = (bf16_t)p0v[ri];
            pbuf[g * 4 + ri][16 + m16] = (bf16_t)p1v[ri];
        }
        __syncthreads();
        bf16x8 ap = *(const bf16x8*)(&pbuf[m16][g * 8]);

#pragma unroll
        for (int ht = 0; ht < 8; ht++) {
            bf16x8 bv = *(const bf16x8*)(vb + (size_t)(ht * 16 + m16) * T + kv0 + g * 8);
            acc[ht] = MFMA16(ap, bv, acc[ht]);
        }
    }

    float* ob = out + (size_t)b * T * H;
#pragma unroll
    for (int ri = 0; ri < 4; ri++) {
        const float inv = 1.f / lst[ri];
        const int row = q0 + g * 4 + ri;
#pragma unroll
        for (int ht = 0; ht < 8; ht++)
            ob[(size_t)row * H + ht * 16 + m16] = acc[ht][ri] * inv;
    }
}

// ---------------------------------------------------------------------------
extern "C" void kernel_launch(void* const* d_in, const int* in_sizes, int n_in,
                              void* d_out, int out_size, void* d_ws, size_t ws_size,
                              hipStream_t stream) {
    const float* x = (const float*)d_in[0];
    const float* Wq = (const float*)d_in[1];
    const float* Wk = (const float*)d_in[2];
    const float* Wv = (const float*)d_in[3];
    float* out = (float*)d_out;  // fp32 output per reference dtype

    char* ws = (char*)d_ws;
    bf16_t* Wt = (bf16_t*)ws;                    // 768 KiB
    char* p = ws + 786432;
    bf16_t* qb = (bf16_t*)(p);                   // 2 MiB each
    bf16_t* kb = (bf16_t*)(p + 2097152);
    bf16_t* vt = (bf16_t*)(p + 2 * 2097152);     // Vt[B][H][T]

    hipLaunchKernelGGL(transpose_w, dim3(C / 32, H / 32, 3), dim3(32, 8), 0, stream,
                       Wq, Wk, Wv, Wt);
    hipLaunchKernelGGL(proj_gemm, dim3(64, 1, 3), dim3(256), 0, stream,
                       x, Wt, qb, kb, vt);
    hipLaunchKernelGGL(attn, dim3(512), dim3(64), 0, stream,
                       qb, kb, vt, out);
}

// Round 5
// 189.578 us; speedup vs baseline: 1.5122x; 1.5122x over previous
//
#include <hip/hip_runtime.h>
#include <hip/hip_bf16.h>
#include <cstdint>

// Problem: single attention head, B=4 T=2048 C=1024 H=128, causal, scale = C^-0.5.
// Inputs fp32: x[B,T,C], Wq/Wk/Wv[C,H], mask[T,T] int32 (tril, ignored).
// Output fp32 [B,T,H].
//
// R5: attack occupancy starvation (R4: attn 2.97% occ, proj 0.75 blocks/CU).
//   1) transpose_w: Wt[3][H][C] bf16
//   2) proj_gemm:   16 rows/wave, 384 blocks, A-prefetch -> q,k bf16, Vt[B,H,T]
//   3) attn:        4-way in-block KV split, 2048 waves, LDS combine

typedef __bf16 bf16_t;
typedef __bf16 bf16x8 __attribute__((ext_vector_type(8)));
typedef float f32x4 __attribute__((ext_vector_type(4)));

#define MFMA16(a, b, c) __builtin_amdgcn_mfma_f32_16x16x32_bf16(a, b, c, 0, 0, 0)

constexpr int T = 2048;
constexpr int C = 1024;
constexpr int H = 128;

__device__ inline bf16x8 load8f(const float* __restrict__ p) {
    float4 a = *(const float4*)p;
    float4 b = *(const float4*)(p + 4);
    bf16x8 r;
    r[0] = (bf16_t)a.x; r[1] = (bf16_t)a.y; r[2] = (bf16_t)a.z; r[3] = (bf16_t)a.w;
    r[4] = (bf16_t)b.x; r[5] = (bf16_t)b.y; r[6] = (bf16_t)b.z; r[7] = (bf16_t)b.w;
    return r;
}

// ---------------------------------------------------------------------------
// Kernel 1: W[C][H] fp32 -> Wt[H][C] bf16. grid (C/32, H/32, 3), block (32,8)
__global__ void transpose_w(const float* __restrict__ Wq,
                            const float* __restrict__ Wk,
                            const float* __restrict__ Wv,
                            bf16_t* __restrict__ Wt) {
    __shared__ bf16_t tile[32][34];
    const float* W = blockIdx.z == 0 ? Wq : (blockIdx.z == 1 ? Wk : Wv);
    const int c0 = blockIdx.x * 32, h0 = blockIdx.y * 32;
    const int tx = threadIdx.x, ty = threadIdx.y;
#pragma unroll
    for (int i = 0; i < 4; i++)
        tile[ty + 8 * i][tx] = (bf16_t)W[(size_t)(c0 + ty + 8 * i) * H + h0 + tx];
    __syncthreads();
    bf16_t* Wtz = Wt + (size_t)blockIdx.z * H * C;
#pragma unroll
    for (int i = 0; i < 4; i++)
        Wtz[(size_t)(h0 + ty + 8 * i) * C + c0 + tx] = tile[tx][ty + 8 * i];
}

// ---------------------------------------------------------------------------
// Kernel 2: y = x @ W, bf16 MFMA. M=8192 K=1024 N=128.
// 16 rows/wave, 4 waves/block. z: 0=q row-major, 1=k row-major, 2=Vt[B][H][T].
// grid (128, 1, 3), block 256. A-loads (HBM fp32) software-prefetched 1 deep.
__global__ __launch_bounds__(256) void proj_gemm(const float* __restrict__ x,
                                                 const bf16_t* __restrict__ Wt,
                                                 bf16_t* __restrict__ qout,
                                                 bf16_t* __restrict__ kout,
                                                 bf16_t* __restrict__ vtout) {
    const int w = threadIdx.x >> 6;
    const int lane = threadIdx.x & 63;
    const int m16 = lane & 15, g = lane >> 4;
    const int z = blockIdx.z;
    const int r0 = blockIdx.x * 64 + w * 16;
    const bf16_t* Wtz = Wt + (size_t)z * H * C;

    f32x4 zero = {0.f, 0.f, 0.f, 0.f};
    f32x4 acc[8];
#pragma unroll
    for (int nt = 0; nt < 8; nt++) acc[nt] = zero;

    const float* xrow = x + (size_t)(r0 + m16) * C + g * 8;
    bf16x8 a = load8f(xrow);
    for (int k0 = 0; k0 < C - 32; k0 += 32) {
        bf16x8 an = load8f(xrow + k0 + 32);   // prefetch next kstep (HBM)
#pragma unroll
        for (int nt = 0; nt < 8; nt++) {
            bf16x8 b = *(const bf16x8*)(Wtz + (size_t)(nt * 16 + m16) * C + k0 + g * 8);
            acc[nt] = MFMA16(a, b, acc[nt]);
        }
        a = an;
    }
    {
        const int k0 = C - 32;
#pragma unroll
        for (int nt = 0; nt < 8; nt++) {
            bf16x8 b = *(const bf16x8*)(Wtz + (size_t)(nt * 16 + m16) * C + k0 + g * 8);
            acc[nt] = MFMA16(a, b, acc[nt]);
        }
    }

    if (z < 2) {
        bf16_t* out = (z == 0) ? qout : kout;
#pragma unroll
        for (int nt = 0; nt < 8; nt++)
#pragma unroll
            for (int ri = 0; ri < 4; ri++) {
                int r = r0 + g * 4 + ri;
                out[(size_t)r * H + nt * 16 + m16] = (bf16_t)acc[nt][ri];
            }
    } else {
#pragma unroll
        for (int ri = 0; ri < 4; ri++) {
            int r = r0 + g * 4 + ri;
            int b = r >> 11, t = r & (T - 1);
#pragma unroll
            for (int nt = 0; nt < 8; nt++)
                vtout[((size_t)b * H + nt * 16 + m16) * T + t] = (bf16_t)acc[nt][ri];
        }
    }
}

// ---------------------------------------------------------------------------
// Kernel 3: flash attention, causal, 4-way in-block KV split.
// Block (256 thr = 4 waves) per (batch, 16-row Q tile); wave w owns KV tiles
// kv0 = 32w + 128j. Private (m,l,acc) per wave; LDS combine at end.
// grid (512), block (256).
__global__ __launch_bounds__(256) void attn(const bf16_t* __restrict__ q,
                                            const bf16_t* __restrict__ k,
                                            const bf16_t* __restrict__ vt,
                                            float* __restrict__ out) {
    __shared__ float accw[4][16][128];            // 32 KiB, scaled partial O
    __shared__ __align__(16) bf16_t pbuf[4][16][40];
    __shared__ float mred[4][16], lred[4][16];
    const int w = threadIdx.x >> 6;
    const int lane = threadIdx.x & 63;
    const int m16 = lane & 15, g = lane >> 4;
    const int b = blockIdx.x & 3;
    const int kk = blockIdx.x >> 2;               // 0..127
    const int qt = (kk < 64) ? kk : 191 - kk;     // reverse-pair load balance
    const int q0 = qt * 16;

    const bf16_t* qb = q + (size_t)b * T * H;
    const bf16_t* kb = k + (size_t)b * T * H;
    const bf16_t* vb = vt + (size_t)b * H * T;

    bf16x8 aq[4];
#pragma unroll
    for (int c = 0; c < 4; c++)
        aq[c] = *(const bf16x8*)(qb + (size_t)(q0 + m16) * H + c * 32 + g * 8);

    f32x4 zero = {0.f, 0.f, 0.f, 0.f};
    f32x4 acc[8];
#pragma unroll
    for (int ht = 0; ht < 8; ht++) acc[ht] = zero;
    float mst[4], lst[4];
#pragma unroll
    for (int ri = 0; ri < 4; ri++) { mst[ri] = -1e30f; lst[ri] = 0.f; }

    const int kv_end = q0 + 16;
    for (int kv0 = w * 32; kv0 < kv_end; kv0 += 128) {
        f32x4 s[2];
        s[0] = zero; s[1] = zero;
#pragma unroll
        for (int t = 0; t < 2; t++)
#pragma unroll
            for (int c = 0; c < 4; c++) {
                bf16x8 bk = *(const bf16x8*)(kb + (size_t)(kv0 + t * 16 + m16) * H + c * 32 + g * 8);
                s[t] = MFMA16(aq[c], bk, s[t]);
            }

        float p0v[4], p1v[4];
#pragma unroll
        for (int ri = 0; ri < 4; ri++) {
            const int row = q0 + g * 4 + ri;
            float v0 = s[0][ri] * 0.03125f;   // C^-0.5 = 1/32
            float v1 = s[1][ri] * 0.03125f;
            if (kv0 + m16 > row) v0 = -1e30f;
            if (kv0 + 16 + m16 > row) v1 = -1e30f;
            float rm = fmaxf(v0, v1);
#pragma unroll
            for (int off = 1; off < 16; off <<= 1) rm = fmaxf(rm, __shfl_xor(rm, off));
            const float mnew = fmaxf(mst[ri], rm);
            const float alpha = __expf(mst[ri] - mnew);
            const float p0 = __expf(v0 - mnew);
            const float p1 = __expf(v1 - mnew);
            float psum = p0 + p1;
#pragma unroll
            for (int off = 1; off < 16; off <<= 1) psum += __shfl_xor(psum, off);
            lst[ri] = lst[ri] * alpha + psum;
            mst[ri] = mnew;
            p0v[ri] = p0; p1v[ri] = p1;
#pragma unroll
            for (int ht = 0; ht < 8; ht++) acc[ht][ri] *= alpha;
        }

        // P: C/D layout -> LDS -> A layout (per-wave buffer; intra-wave
        // ordering enforced by same-lane aliasing -> compiler lgkmcnt)
#pragma unroll
        for (int ri = 0; ri < 4; ri++) {
            pbuf[w][g * 4 + ri][m16] = (bf16_t)p0v[ri];
            pbuf[w][g * 4 + ri][16 + m16] = (bf16_t)p1v[ri];
        }
        bf16x8 ap = *(const bf16x8*)(&pbuf[w][m16][g * 8]);

#pragma unroll
        for (int ht = 0; ht < 8; ht++) {
            bf16x8 bv = *(const bf16x8*)(vb + (size_t)(ht * 16 + m16) * T + kv0 + g * 8);
            acc[ht] = MFMA16(ap, bv, acc[ht]);
        }
    }

    // ---- cross-wave combine: O = sum_w e^{m_w-m*} acc_w, l* likewise ----
    if (m16 == 0) {
#pragma unroll
        for (int ri = 0; ri < 4; ri++) mred[w][g * 4 + ri] = mst[ri];
    }
    __syncthreads();
    float scale[4];
#pragma unroll
    for (int ri = 0; ri < 4; ri++) {
        const int row = g * 4 + ri;
        float mt = fmaxf(fmaxf(mred[0][row], mred[1][row]),
                         fmaxf(mred[2][row], mred[3][row]));
        scale[ri] = __expf(mst[ri] - mt);
    }
    if (m16 == 0) {
#pragma unroll
        for (int ri = 0; ri < 4; ri++) lred[w][g * 4 + ri] = lst[ri] * scale[ri];
    }
#pragma unroll
    for (int ht = 0; ht < 8; ht++)
#pragma unroll
        for (int ri = 0; ri < 4; ri++)
            accw[w][g * 4 + ri][ht * 16 + m16] = acc[ht][ri] * scale[ri];
    __syncthreads();

    float* ob = out + ((size_t)b * T + q0) * H;
    for (int e = threadIdx.x; e < 16 * 128; e += 256) {
        const int row = e >> 7, col = e & 127;
        float o = accw[0][row][col] + accw[1][row][col] +
                  accw[2][row][col] + accw[3][row][col];
        float l = lred[0][row] + lred[1][row] + lred[2][row] + lred[3][row];
        ob[(size_t)row * H + col] = o / l;
    }
}

// ---------------------------------------------------------------------------
extern "C" void kernel_launch(void* const* d_in, const int* in_sizes, int n_in,
                              void* d_out, int out_size, void* d_ws, size_t ws_size,
                              hipStream_t stream) {
    const float* x = (const float*)d_in[0];
    const float* Wq = (const float*)d_in[1];
    const float* Wk = (const float*)d_in[2];
    const float* Wv = (const float*)d_in[3];
    float* out = (float*)d_out;

    char* ws = (char*)d_ws;
    bf16_t* Wt = (bf16_t*)ws;                    // 768 KiB
    char* p = ws + 786432;
    bf16_t* qb = (bf16_t*)(p);                   // 2 MiB each
    bf16_t* kb = (bf16_t*)(p + 2097152);
    bf16_t* vt = (bf16_t*)(p + 2 * 2097152);     // Vt[B][H][T]

    hipLaunchKernelGGL(transpose_w, dim3(C / 32, H / 32, 3), dim3(32, 8), 0, stream,
                       Wq, Wk, Wv, Wt);
    hipLaunchKernelGGL(proj_gemm, dim3(128, 1, 3), dim3(256), 0, stream,
                       x, Wt, qb, kb, vt);
    hipLaunchKernelGGL(attn, dim3(512), dim3(256), 0, stream,
                       qb, kb, vt, out);
}

// Round 6
// 170.038 us; speedup vs baseline: 1.6860x; 1.1149x over previous
//
#include <hip/hip_runtime.h>
#include <hip/hip_bf16.h>
#include <cstdint>

// Problem: single attention head, B=4 T=2048 C=1024 H=128, causal, scale = C^-0.5.
// Inputs fp32: x[B,T,C], Wq/Wk/Wv[C,H], mask[T,T] int32 (tril, ignored).
// Output fp32 [B,T,H].
//
// R6: proj was latency-bound on fp32 HBM A-loads (460 GB/s eff, MfmaUtil 3%).
//   0) convert_x: x fp32 -> xb bf16 (streamed once at HBM BW)
//   1) transpose_w: Wt[3][H][C] bf16
//   2) proj_gemm v2: merged-z, 32x64/wave, bf16 A from L3, 1-deep pipeline
//   3) attn: R5 split-KV-4 + ones-column l-accumulation (no psum shuffles)

typedef __bf16 bf16_t;
typedef __bf16 bf16x4 __attribute__((ext_vector_type(4)));
typedef __bf16 bf16x8 __attribute__((ext_vector_type(8)));
typedef float f32x4 __attribute__((ext_vector_type(4)));

#define MFMA16(a, b, c) __builtin_amdgcn_mfma_f32_16x16x32_bf16(a, b, c, 0, 0, 0)

constexpr int T = 2048;
constexpr int C = 1024;
constexpr int H = 128;

__device__ inline bf16x8 load8f(const float* __restrict__ p) {
    float4 a = *(const float4*)p;
    float4 b = *(const float4*)(p + 4);
    bf16x8 r;
    r[0] = (bf16_t)a.x; r[1] = (bf16_t)a.y; r[2] = (bf16_t)a.z; r[3] = (bf16_t)a.w;
    r[4] = (bf16_t)b.x; r[5] = (bf16_t)b.y; r[6] = (bf16_t)b.z; r[7] = (bf16_t)b.w;
    return r;
}

// ---------------------------------------------------------------------------
// Kernel 0: x fp32 -> bf16, streamed. grid 2048, block 256.
__global__ __launch_bounds__(256) void convert_x(const float* __restrict__ x,
                                                 bf16_t* __restrict__ xb, int n8) {
    int i = blockIdx.x * 256 + threadIdx.x;
    const int stride = gridDim.x * 256;
    for (; i < n8; i += stride)
        *(bf16x8*)(xb + (size_t)i * 8) = load8f(x + (size_t)i * 8);
}

// ---------------------------------------------------------------------------
// Kernel 1: W[C][H] fp32 -> Wt[H][C] bf16. grid (C/32, H/32, 3), block (32,8)
__global__ void transpose_w(const float* __restrict__ Wq,
                            const float* __restrict__ Wk,
                            const float* __restrict__ Wv,
                            bf16_t* __restrict__ Wt) {
    __shared__ bf16_t tile[32][34];
    const float* W = blockIdx.z == 0 ? Wq : (blockIdx.z == 1 ? Wk : Wv);
    const int c0 = blockIdx.x * 32, h0 = blockIdx.y * 32;
    const int tx = threadIdx.x, ty = threadIdx.y;
#pragma unroll
    for (int i = 0; i < 4; i++)
        tile[ty + 8 * i][tx] = (bf16_t)W[(size_t)(c0 + ty + 8 * i) * H + h0 + tx];
    __syncthreads();
    bf16_t* Wtz = Wt + (size_t)blockIdx.z * H * C;
#pragma unroll
    for (int i = 0; i < 4; i++)
        Wtz[(size_t)(h0 + ty + 8 * i) * C + c0 + tx] = tile[tx][ty + 8 * i];
}

// ---------------------------------------------------------------------------
// Kernel 2: y = xb @ W, bf16 MFMA, merged z. M=8192 K=1024 N=128 per z.
// Block = 64 rows x 128 cols (z), 4 waves of 32x64 (2 m-frags x 4 n-frags).
// grid (128, 3), block 256. 1-deep software pipeline on A+B loads.
__global__ __launch_bounds__(256) void proj_gemm(const bf16_t* __restrict__ xb,
                                                 const bf16_t* __restrict__ Wt,
                                                 bf16_t* __restrict__ qout,
                                                 bf16_t* __restrict__ kout,
                                                 bf16_t* __restrict__ vtout) {
    const int w = threadIdx.x >> 6;
    const int wm = w & 1, wn = w >> 1;
    const int lane = threadIdx.x & 63;
    const int m16 = lane & 15, g = lane >> 4;
    const int z = blockIdx.y;
    const int m0 = blockIdx.x * 64 + wm * 32;
    const int n0 = wn * 64;                       // within z's 128 cols

    const bf16_t* arow = xb + (size_t)(m0 + m16) * C + g * 8;
    const bf16_t* brow = Wt + (size_t)(z * H + n0 + m16) * C + g * 8;

    f32x4 zero = {0.f, 0.f, 0.f, 0.f};
    f32x4 acc[2][4];
#pragma unroll
    for (int mf = 0; mf < 2; mf++)
#pragma unroll
        for (int nf = 0; nf < 4; nf++) acc[mf][nf] = zero;

    bf16x8 a0 = *(const bf16x8*)(arow);
    bf16x8 a1 = *(const bf16x8*)(arow + 16 * C);
    bf16x8 bb[4];
#pragma unroll
    for (int nf = 0; nf < 4; nf++) bb[nf] = *(const bf16x8*)(brow + (size_t)nf * 16 * C);

    for (int k0 = 0; k0 < C - 32; k0 += 32) {
        bf16x8 na0 = *(const bf16x8*)(arow + k0 + 32);
        bf16x8 na1 = *(const bf16x8*)(arow + 16 * C + k0 + 32);
        bf16x8 nb[4];
#pragma unroll
        for (int nf = 0; nf < 4; nf++)
            nb[nf] = *(const bf16x8*)(brow + (size_t)nf * 16 * C + k0 + 32);
#pragma unroll
        for (int nf = 0; nf < 4; nf++) {
            acc[0][nf] = MFMA16(a0, bb[nf], acc[0][nf]);
            acc[1][nf] = MFMA16(a1, bb[nf], acc[1][nf]);
        }
        a0 = na0; a1 = na1;
#pragma unroll
        for (int nf = 0; nf < 4; nf++) bb[nf] = nb[nf];
    }
#pragma unroll
    for (int nf = 0; nf < 4; nf++) {
        acc[0][nf] = MFMA16(a0, bb[nf], acc[0][nf]);
        acc[1][nf] = MFMA16(a1, bb[nf], acc[1][nf]);
    }

    if (z < 2) {
        bf16_t* out = (z == 0) ? qout : kout;
#pragma unroll
        for (int mf = 0; mf < 2; mf++)
#pragma unroll
            for (int nf = 0; nf < 4; nf++)
#pragma unroll
                for (int ri = 0; ri < 4; ri++) {
                    int r = m0 + mf * 16 + g * 4 + ri;
                    out[(size_t)r * H + n0 + nf * 16 + m16] = (bf16_t)acc[mf][nf][ri];
                }
    } else {
#pragma unroll
        for (int mf = 0; mf < 2; mf++) {
            const int t0 = m0 + mf * 16 + g * 4;     // 4 consecutive t, same batch
            const int bidx = t0 >> 11, t = t0 & (T - 1);
#pragma unroll
            for (int nf = 0; nf < 4; nf++) {
                const int h = n0 + nf * 16 + m16;
                bf16x4 v;
#pragma unroll
                for (int ri = 0; ri < 4; ri++) v[ri] = (bf16_t)acc[mf][nf][ri];
                *(bf16x4*)(vtout + ((size_t)bidx * H + h) * T + t) = v;
            }
        }
    }
}

// ---------------------------------------------------------------------------
// Kernel 3: flash attention, causal, 4-way in-block KV split + ones-column l.
// Block (256 thr = 4 waves) per (batch, 16-row Q tile); wave w owns KV tiles
// kv0 = 32w + 128j. acc[8] = l-accumulator via PV with B = ones.
// grid (512), block (256).
__global__ __launch_bounds__(256) void attn(const bf16_t* __restrict__ q,
                                            const bf16_t* __restrict__ k,
                                            const bf16_t* __restrict__ vt,
                                            float* __restrict__ out) {
    __shared__ float accw[4][16][128];            // 32 KiB, scaled partial O
    __shared__ __align__(16) bf16_t pbuf[4][16][40];
    __shared__ float mred[4][16], lred[4][16];
    const int w = threadIdx.x >> 6;
    const int lane = threadIdx.x & 63;
    const int m16 = lane & 15, g = lane >> 4;
    const int b = blockIdx.x & 3;
    const int kk = blockIdx.x >> 2;               // 0..127
    const int qt = (kk < 64) ? kk : 191 - kk;     // reverse-pair load balance
    const int q0 = qt * 16;

    const bf16_t* qb = q + (size_t)b * T * H;
    const bf16_t* kb = k + (size_t)b * T * H;
    const bf16_t* vb = vt + (size_t)b * H * T;

    bf16x8 aq[4];
#pragma unroll
    for (int c = 0; c < 4; c++)
        aq[c] = *(const bf16x8*)(qb + (size_t)(q0 + m16) * H + c * 32 + g * 8);

    bf16x8 ones;
#pragma unroll
    for (int j = 0; j < 8; j++) ones[j] = (bf16_t)1.0f;

    f32x4 zero = {0.f, 0.f, 0.f, 0.f};
    f32x4 acc[9];                                 // [8] = row-sum (l) accumulator
#pragma unroll
    for (int ht = 0; ht < 9; ht++) acc[ht] = zero;
    float mst[4];
#pragma unroll
    for (int ri = 0; ri < 4; ri++) mst[ri] = -1e30f;

    const int kv_end = q0 + 16;
    for (int kv0 = w * 32; kv0 < kv_end; kv0 += 128) {
        f32x4 s[2];
        s[0] = zero; s[1] = zero;
#pragma unroll
        for (int t = 0; t < 2; t++)
#pragma unroll
            for (int c = 0; c < 4; c++) {
                bf16x8 bk = *(const bf16x8*)(kb + (size_t)(kv0 + t * 16 + m16) * H + c * 32 + g * 8);
                s[t] = MFMA16(aq[c], bk, s[t]);
            }

        float p0v[4], p1v[4];
#pragma unroll
        for (int ri = 0; ri < 4; ri++) {
            const int row = q0 + g * 4 + ri;
            float v0 = s[0][ri] * 0.03125f;       // C^-0.5 = 1/32
            float v1 = s[1][ri] * 0.03125f;
            if (kv0 + m16 > row) v0 = -1e30f;
            if (kv0 + 16 + m16 > row) v1 = -1e30f;
            float rm = fmaxf(v0, v1);
#pragma unroll
            for (int off = 1; off < 16; off <<= 1) rm = fmaxf(rm, __shfl_xor(rm, off));
            const float mnew = fmaxf(mst[ri], rm);
            const float alpha = __expf(mst[ri] - mnew);
            mst[ri] = mnew;
            p0v[ri] = __expf(v0 - mnew);
            p1v[ri] = __expf(v1 - mnew);
#pragma unroll
            for (int ht = 0; ht < 9; ht++) acc[ht][ri] *= alpha;
        }

        // P: C/D layout -> per-wave LDS -> A layout (same-wave DS ordering)
#pragma unroll
        for (int ri = 0; ri < 4; ri++) {
            pbuf[w][g * 4 + ri][m16] = (bf16_t)p0v[ri];
            pbuf[w][g * 4 + ri][16 + m16] = (bf16_t)p1v[ri];
        }
        bf16x8 ap = *(const bf16x8*)(&pbuf[w][m16][g * 8]);

#pragma unroll
        for (int ht = 0; ht < 8; ht++) {
            bf16x8 bv = *(const bf16x8*)(vb + (size_t)(ht * 16 + m16) * T + kv0 + g * 8);
            acc[ht] = MFMA16(ap, bv, acc[ht]);
        }
        acc[8] = MFMA16(ap, ones, acc[8]);        // l += row-sum(P)
    }

    // ---- cross-wave combine ----
    if (m16 == 0) {
#pragma unroll
        for (int ri = 0; ri < 4; ri++) mred[w][g * 4 + ri] = mst[ri];
    }
    __syncthreads();
    float scale[4];
#pragma unroll
    for (int ri = 0; ri < 4; ri++) {
        const int row = g * 4 + ri;
        float mt = fmaxf(fmaxf(mred[0][row], mred[1][row]),
                         fmaxf(mred[2][row], mred[3][row]));
        scale[ri] = __expf(mst[ri] - mt);
    }
    if (m16 == 0) {
#pragma unroll
        for (int ri = 0; ri < 4; ri++) lred[w][g * 4 + ri] = acc[8][ri] * scale[ri];
    }
#pragma unroll
    for (int ht = 0; ht < 8; ht++)
#pragma unroll
        for (int ri = 0; ri < 4; ri++)
            accw[w][g * 4 + ri][ht * 16 + m16] = acc[ht][ri] * scale[ri];
    __syncthreads();

    float* ob = out + ((size_t)b * T + q0) * H;
    for (int e = threadIdx.x; e < 16 * 128; e += 256) {
        const int row = e >> 7, col = e & 127;
        float o = accw[0][row][col] + accw[1][row][col] +
                  accw[2][row][col] + accw[3][row][col];
        float l = lred[0][row] + lred[1][row] + lred[2][row] + lred[3][row];
        ob[(size_t)row * H + col] = o / l;
    }
}

// ---------------------------------------------------------------------------
extern "C" void kernel_launch(void* const* d_in, const int* in_sizes, int n_in,
                              void* d_out, int out_size, void* d_ws, size_t ws_size,
                              hipStream_t stream) {
    const float* x = (const float*)d_in[0];
    const float* Wq = (const float*)d_in[1];
    const float* Wk = (const float*)d_in[2];
    const float* Wv = (const float*)d_in[3];
    float* out = (float*)d_out;

    char* ws = (char*)d_ws;
    bf16_t* xb = (bf16_t*)ws;                     // 16 MiB
    bf16_t* Wt = (bf16_t*)(ws + 16777216);        // 768 KiB
    char* p = ws + 16777216 + 786432;
    bf16_t* qb = (bf16_t*)(p);                    // 2 MiB each
    bf16_t* kb = (bf16_t*)(p + 2097152);
    bf16_t* vt = (bf16_t*)(p + 2 * 2097152);      // Vt[B][H][T]

    hipLaunchKernelGGL(convert_x, dim3(2048), dim3(256), 0, stream,
                       x, xb, (int)((size_t)4 * T * C / 8));
    hipLaunchKernelGGL(transpose_w, dim3(C / 32, H / 32, 3), dim3(32, 8), 0, stream,
                       Wq, Wk, Wv, Wt);
    hipLaunchKernelGGL(proj_gemm, dim3(128, 3), dim3(256), 0, stream,
                       xb, Wt, qb, kb, vt);
    hipLaunchKernelGGL(attn, dim3(512), dim3(256), 0, stream,
                       qb, kb, vt, out);
}